// Round 8
// baseline (550.193 us; speedup 1.0000x reference)
//
#include <hip/hip_runtime.h>
#include <hip/hip_bf16.h>

#define N_TOK 16384
#define D_DIM 1024
#define E_NUM 8
#define H_DIM 2048
#define MT 32          // tokens per scalar-fallback FFN tile
#define FFN_BLK 512

typedef __attribute__((ext_vector_type(8))) short short8;
typedef __attribute__((ext_vector_type(4))) float floatx4;

__device__ __forceinline__ unsigned short f2bf_bits(float f) {
    __hip_bfloat16 h = __float2bfloat16(f);   // RNE
    return *reinterpret_cast<unsigned short*>(&h);
}

// async global->LDS, 16B per lane; LDS dest = wave-uniform base + lane*16
__device__ __forceinline__ void async16(const void* g, void* l) {
    __builtin_amdgcn_global_load_lds(
        (const __attribute__((address_space(1))) unsigned int*)g,
        (__attribute__((address_space(3))) unsigned int*)l,
        16, 0, 0);
}

// ---------------------------------------------------------------------------
// K1: fused gate + weight transpose-cast (independent work, one launch).
// blocks [0,8192): W1/W2 transpose+cast. blocks [8192,12288): gating.
// Gate does NOT write xb: the scatter_gather kernel casts x -> sorted xs
// (r4-measured best; r6's toksort-gather-in-ffn1 regressed ffn1 by ~25us).
// ---------------------------------------------------------------------------
__global__ __launch_bounds__(256) void moe_gate_transpose_fused(
    const float* __restrict__ x,
    const float* __restrict__ Wg,
    const float* __restrict__ bg,
    float* __restrict__ gw_out,
    float* __restrict__ topw,
    int* __restrict__ topidx,
    const float* __restrict__ W1,
    const float* __restrict__ W2,
    unsigned short* __restrict__ W1t,
    unsigned short* __restrict__ W2t) {

    __shared__ float tile[64][65];

    if (blockIdx.x < 8192) {
        // ---- transpose branch ----
        int id = blockIdx.x;
        const float* in; unsigned short* out; int R, C, cx, ry, e;
        if (id < 4096) {
            e = id >> 9; int t = id & 511;
            in = W1; out = W1t; R = 1024; C = 2048;
            cx = t & 31; ry = t >> 5;
        } else {
            id -= 4096;
            e = id >> 9; int t = id & 511;
            in = W2; out = W2t; R = 2048; C = 1024;
            cx = t & 15; ry = t >> 4;
        }
        const float* inE = in + (size_t)e * 2097152;
        unsigned short* outE = out + (size_t)e * 2097152;
        int c0 = cx << 6, r0 = ry << 6;
        int tr = threadIdx.x >> 4;
        int tc = (threadIdx.x & 15) << 2;
#pragma unroll
        for (int i = 0; i < 4; i++) {
            int r = tr + (i << 4);
            float4 v = *(const float4*)(inE + (size_t)(r0 + r) * C + c0 + tc);
            tile[r][tc + 0] = v.x; tile[r][tc + 1] = v.y;
            tile[r][tc + 2] = v.z; tile[r][tc + 3] = v.w;
        }
        __syncthreads();
#pragma unroll
        for (int it = 0; it < 2; it++) {
            int task = threadIdx.x + (it << 8);
            int c = task >> 3, rr = (task & 7) << 3;
            short8 o;
#pragma unroll
            for (int j = 0; j < 8; j++)
                ((unsigned short*)&o)[j] = f2bf_bits(tile[rr + j][c]);
            *(short8*)(outE + (size_t)(c0 + c) * R + r0 + rr) = o;
        }
        return;
    }

    // ---- gate branch: one wave per token ----
    int bid = blockIdx.x - 8192;
    int wave = ((bid << 8) + threadIdx.x) >> 6;
    int lane = threadIdx.x & 63;
    if (wave >= N_TOK) return;
    const float* xr = x + (size_t)wave * D_DIM;

    float4 xv[4];
#pragma unroll
    for (int i = 0; i < 4; i++)
        xv[i] = *(const float4*)(xr + i * 256 + lane * 4);

    float acc[8];
#pragma unroll
    for (int e = 0; e < 8; e++) acc[e] = 0.f;

#pragma unroll
    for (int i = 0; i < 4; i++) {
        const float xs4[4] = {xv[i].x, xv[i].y, xv[i].z, xv[i].w};
        const float* wp = Wg + ((size_t)(i * 256) + lane * 4) * 8;
#pragma unroll
        for (int j = 0; j < 4; j++) {
            float4 w0 = *(const float4*)(wp + j * 8);
            float4 w1 = *(const float4*)(wp + j * 8 + 4);
            float s = xs4[j];
            acc[0] += s * w0.x; acc[1] += s * w0.y;
            acc[2] += s * w0.z; acc[3] += s * w0.w;
            acc[4] += s * w1.x; acc[5] += s * w1.y;
            acc[6] += s * w1.z; acc[7] += s * w1.w;
        }
    }
#pragma unroll
    for (int e = 0; e < 8; e++) {
#pragma unroll
        for (int off = 32; off > 0; off >>= 1)
            acc[e] += __shfl_xor(acc[e], off, 64);
    }
#pragma unroll
    for (int e = 0; e < 8; e++) acc[e] += bg[e];

    float mx = acc[0]; int am = 0;
#pragma unroll
    for (int e = 1; e < 8; e++) { if (acc[e] > mx) { mx = acc[e]; am = e; } }
    float w[8], s = 0.f;
#pragma unroll
    for (int e = 0; e < 8; e++) { w[e] = expf(acc[e] - mx); s += w[e]; }
    float inv = 1.f / s;
#pragma unroll
    for (int e = 0; e < 8; e++) w[e] *= inv;

    if (lane == 0) {
        float4 a = make_float4(w[0], w[1], w[2], w[3]);
        float4 b = make_float4(w[4], w[5], w[6], w[7]);
        *(float4*)(gw_out + (size_t)wave * 8)     = a;
        *(float4*)(gw_out + (size_t)wave * 8 + 4) = b;
        topw[wave]   = w[am];
        topidx[wave] = am;
    }
}

// standalone gate for the fallback path
__global__ __launch_bounds__(256) void moe_gate_kernel(
    const float* __restrict__ x,
    const float* __restrict__ Wg,
    const float* __restrict__ bg,
    float* __restrict__ gw_out,
    float* __restrict__ topw,
    int* __restrict__ topidx) {
    int wave = (blockIdx.x * blockDim.x + threadIdx.x) >> 6;
    int lane = threadIdx.x & 63;
    if (wave >= N_TOK) return;
    const float* xr = x + (size_t)wave * D_DIM;

    float4 xv[4];
#pragma unroll
    for (int i = 0; i < 4; i++)
        xv[i] = *(const float4*)(xr + i * 256 + lane * 4);

    float acc[8];
#pragma unroll
    for (int e = 0; e < 8; e++) acc[e] = 0.f;
#pragma unroll
    for (int i = 0; i < 4; i++) {
        const float xs4[4] = {xv[i].x, xv[i].y, xv[i].z, xv[i].w};
        const float* wp = Wg + ((size_t)(i * 256) + lane * 4) * 8;
#pragma unroll
        for (int j = 0; j < 4; j++) {
            float4 w0 = *(const float4*)(wp + j * 8);
            float4 w1 = *(const float4*)(wp + j * 8 + 4);
            float s = xs4[j];
            acc[0] += s * w0.x; acc[1] += s * w0.y;
            acc[2] += s * w0.z; acc[3] += s * w0.w;
            acc[4] += s * w1.x; acc[5] += s * w1.y;
            acc[6] += s * w1.z; acc[7] += s * w1.w;
        }
    }
#pragma unroll
    for (int e = 0; e < 8; e++) {
#pragma unroll
        for (int off = 32; off > 0; off >>= 1)
            acc[e] += __shfl_xor(acc[e], off, 64);
    }
#pragma unroll
    for (int e = 0; e < 8; e++) acc[e] += bg[e];

    float mx = acc[0]; int am = 0;
#pragma unroll
    for (int e = 1; e < 8; e++) { if (acc[e] > mx) { mx = acc[e]; am = e; } }
    float w[8], s = 0.f;
#pragma unroll
    for (int e = 0; e < 8; e++) { w[e] = expf(acc[e] - mx); s += w[e]; }
    float inv = 1.f / s;
#pragma unroll
    for (int e = 0; e < 8; e++) w[e] *= inv;

    if (lane == 0) {
        float4 a = make_float4(w[0], w[1], w[2], w[3]);
        float4 b = make_float4(w[4], w[5], w[6], w[7]);
        *(float4*)(gw_out + (size_t)wave * 8)     = a;
        *(float4*)(gw_out + (size_t)wave * 8 + 4) = b;
        topw[wave]   = w[am];
        topidx[wave] = am;
    }
}

// K2: single-block histogram+scan, int4 loads
__global__ __launch_bounds__(256) void moe_hist_scan_kernel(
    const int* __restrict__ topidx,
    int* __restrict__ offsets,
    int* __restrict__ cursor) {
    __shared__ int part[256][8];
    int tid = threadIdx.x;
    int c0 = 0, c1 = 0, c2 = 0, c3 = 0, c4 = 0, c5 = 0, c6 = 0, c7 = 0;
    const int4* tp = (const int4*)topidx;
    for (int i = 0; i < N_TOK / 1024; i++) {
        int4 v = tp[tid + (i << 8)];
#pragma unroll
        for (int j = 0; j < 4; j++) {
            int idx = (&v.x)[j];
            c0 += (idx == 0); c1 += (idx == 1); c2 += (idx == 2); c3 += (idx == 3);
            c4 += (idx == 4); c5 += (idx == 5); c6 += (idx == 6); c7 += (idx == 7);
        }
    }
    part[tid][0] = c0; part[tid][1] = c1; part[tid][2] = c2; part[tid][3] = c3;
    part[tid][4] = c4; part[tid][5] = c5; part[tid][6] = c6; part[tid][7] = c7;
    __syncthreads();
    for (int s = 128; s > 0; s >>= 1) {
        if (tid < s) {
#pragma unroll
            for (int e = 0; e < 8; e++) part[tid][e] += part[tid + s][e];
        }
        __syncthreads();
    }
    if (tid == 0) {
        int run = 0;
        for (int e = 0; e < 8; e++) {
            offsets[e] = run;
            cursor[e]  = run;
            run += part[0][e];
        }
        offsets[8] = run;
    }
}

// K3: scatter + cast + gather fused (r4-verified). Block owns 64 tokens;
// LDS-atomic local rank + 8 global atomics, then xs[p] = bf16(x[t]).
// ffn1 then reads SORTED xs linearly (keeps A-panel L2 locality).
__global__ __launch_bounds__(256) void moe_scatter_gather(
    const float* __restrict__ x,
    const int* __restrict__ topidx,
    int* __restrict__ cursor,
    int* __restrict__ toksort,
    unsigned short* __restrict__ xs) {
    __shared__ int lcnt[8];
    __shared__ int lbase[8];
    __shared__ int s_pos[64];
    int tid = threadIdx.x;
    int base = blockIdx.x << 6;
    if (tid < 8) lcnt[tid] = 0;
    __syncthreads();
    int e = 0, r = 0;
    if (tid < 64) {
        e = topidx[base + tid];
        r = atomicAdd(&lcnt[e], 1);   // LDS atomic
    }
    __syncthreads();
    if (tid < 8) lbase[tid] = atomicAdd(&cursor[tid], lcnt[tid]);
    __syncthreads();
    if (tid < 64) {
        int p = lbase[e] + r;
        toksort[p] = base + tid;
        s_pos[tid] = p;
    }
    __syncthreads();
    for (int rr = 0; rr < 64; rr++) {
        int tok = base + rr;
        int p = s_pos[rr];
        float4 v = *(const float4*)(x + (size_t)tok * D_DIM + (tid << 2));
        ushort4 o;
        o.x = f2bf_bits(v.x); o.y = f2bf_bits(v.y);
        o.z = f2bf_bits(v.z); o.w = f2bf_bits(v.w);
        *(ushort4*)(xs + (size_t)p * D_DIM + (tid << 2)) = o;
    }
}

// fallback scatter (no xs buffer)
__global__ __launch_bounds__(256) void moe_scatter_kernel(
    const int* __restrict__ topidx,
    int* __restrict__ cursor,
    int* __restrict__ toksort) {
    __shared__ int lcnt[8];
    __shared__ int lbase[8];
    int tid = threadIdx.x;
    int t = blockIdx.x * blockDim.x + tid;
    if (tid < 8) lcnt[tid] = 0;
    __syncthreads();
    int e = topidx[t];
    int r = atomicAdd(&lcnt[e], 1);
    __syncthreads();
    if (tid < 8) lbase[tid] = atomicAdd(&cursor[tid], lcnt[tid]);
    __syncthreads();
    toksort[lbase[e] + r] = t;
}

// ---------------------------------------------------------------------------
// MFMA GEMMs: exact round-1 core (best measured: ffn1 130 / ffn2 ~125).
// 128x128 tile, BK=32, 16KB LDS, 4 waves 2x2, 4x4 frags/wave.
// Evidence ledger: +XCD swizzle = -14us (r4, L3-resident regime);
// BK=64 = -occupancy net loss (r5); granule swizzle = counter unchanged,
// conflicts non-binding (r5: 0 conflicts yet slower); toksort-gather in
// staging = -25us (r6). -> none of them; this is the measured optimum.
// frag A: lane l -> A[m=l&15][k=(l>>4)*8+j]; frag B: B[k=(l>>4)*8+j][n=l&15]
// C/D:   row=(l>>4)*4+r, col=l&15   (HW-verified layouts)
// ---------------------------------------------------------------------------
__device__ __forceinline__ int find_tile(const int* offsets, int mt,
                                         int& row0, int& rows) {
    int cum = 0;
    for (int ee = 0; ee < E_NUM; ee++) {
        int o0 = offsets[ee], o1 = offsets[ee + 1];
        int tiles = (o1 - o0 + 127) >> 7;
        if (mt < cum + tiles) {
            row0 = o0 + ((mt - cum) << 7);
            rows = o1 - row0; if (rows > 128) rows = 128;
            return ee;
        }
        cum += tiles;
    }
    return -1;
}

template<int LDK>
__device__ __forceinline__ void gemm128_bk32(
    const unsigned short* __restrict__ Ag,
    const unsigned short* __restrict__ Be,
    int row0, int n0,
    unsigned short* As, unsigned short* Bs,
    floatx4 (&acc)[4][4]) {

    const int tid = threadIdx.x;
    const int l = tid & 63, w = tid >> 6;
    const int wm = w & 1, wn = w >> 1;
    const int lrow = l & 15, lq = l >> 4;
    const int koff = (l & 3) << 3;

    const unsigned short* aptr[2];
    const unsigned short* bptr[2];
#pragma unroll
    for (int i = 0; i < 2; i++) {
        int r = (w << 5) + (i << 4) + (l >> 2);
        int p = row0 + r; if (p > N_TOK - 1) p = N_TOK - 1;
        aptr[i] = Ag + (size_t)p * LDK + koff;
        bptr[i] = Be + (size_t)(n0 + r) * LDK + koff;
    }

    for (int kt = 0; kt < LDK / 32; kt++) {
        const int kb = kt << 5;
        __syncthreads();
#pragma unroll
        for (int i = 0; i < 2; i++) {
            async16(aptr[i] + kb, As + (((w << 5) + (i << 4)) << 5));
            async16(bptr[i] + kb, Bs + (((w << 5) + (i << 4)) << 5));
        }
        __syncthreads();
        short8 af[4], bfv[4];
#pragma unroll
        for (int mi = 0; mi < 4; mi++)
            af[mi] = *(const short8*)(As + (((wm << 6) + (mi << 4) + lrow) << 5) + (lq << 3));
#pragma unroll
        for (int ni = 0; ni < 4; ni++)
            bfv[ni] = *(const short8*)(Bs + (((wn << 6) + (ni << 4) + lrow) << 5) + (lq << 3));
#pragma unroll
        for (int mi = 0; mi < 4; mi++)
#pragma unroll
            for (int ni = 0; ni < 4; ni++)
                acc[mi][ni] = __builtin_amdgcn_mfma_f32_16x16x32_bf16(
                    af[mi], bfv[ni], acc[mi][ni], 0, 0, 0);
    }
}

__global__ __launch_bounds__(256) void moe_ffn1_mfma(
    const unsigned short* __restrict__ xs,    // [N][D] bf16 SORTED order
    const unsigned short* __restrict__ W1t,   // [E][H][D] bf16
    const float* __restrict__ b1,
    const int* __restrict__ offsets,
    unsigned short* __restrict__ hb) {        // [N][H] bf16, sorted order

    // union: staging As(8KB)+Bs(8KB) / epilogue repack 64x132 bf16 (16.9KB)
    __shared__ __align__(16) unsigned short LDS[64 * 132];
    unsigned short* As = LDS;
    unsigned short* Bs = LDS + 4096;

    int row0, rows;
    int e = find_tile(offsets, blockIdx.x, row0, rows);
    if (e < 0) return;
    int n0 = blockIdx.y << 7;

    int tid = threadIdx.x, l = tid & 63, w = tid >> 6;
    int wm = w & 1, wn = w >> 1;
    int lrow = l & 15, lq = l >> 4;

    floatx4 acc[4][4];
#pragma unroll
    for (int mi = 0; mi < 4; mi++)
#pragma unroll
        for (int ni = 0; ni < 4; ni++) acc[mi][ni] = floatx4{0.f, 0.f, 0.f, 0.f};

    gemm128_bk32<D_DIM>(xs, W1t + (size_t)e * H_DIM * D_DIM,
                        row0, n0, As, Bs, acc);

    float bias[4];
#pragma unroll
    for (int ni = 0; ni < 4; ni++)
        bias[ni] = b1[e * H_DIM + n0 + (wn << 6) + (ni << 4) + lrow];

    // epilogue in two 64-row halves: bias+relu+bf16 -> LDS[64][132],
    // then 64B-per-thread coalesced stores (WRITE 125MB -> 66MB, r4-verified)
#pragma unroll
    for (int h = 0; h < 2; h++) {
        __syncthreads();
        if (wm == h) {
#pragma unroll
            for (int ni = 0; ni < 4; ni++) {
                int cl = (wn << 6) + (ni << 4) + lrow;
#pragma unroll
                for (int mi = 0; mi < 4; mi++) {
#pragma unroll
                    for (int r = 0; r < 4; r++) {
                        int rl = (mi << 4) + (lq << 2) + r;   // 0..63
                        float v = acc[mi][ni][r] + bias[ni];
                        v = v > 0.f ? v : 0.f;
                        LDS[rl * 132 + cl] = f2bf_bits(v);
                    }
                }
            }
        }
        __syncthreads();
        int trow = tid >> 2;            // 0..63
        int tcol = (tid & 3) << 5;      // 0,32,64,96
        int grow = (h << 6) + trow;
        if (grow < rows) {
            unsigned short* dst = hb + (size_t)(row0 + grow) * H_DIM + n0 + tcol;
            const unsigned short* src = LDS + trow * 132 + tcol;
#pragma unroll
            for (int i2 = 0; i2 < 4; i2++)
                *(short8*)(dst + i2 * 8) = *(const short8*)(src + i2 * 8);
        }
    }
}

__global__ __launch_bounds__(256) void moe_ffn2_mfma(
    const unsigned short* __restrict__ hb,    // [N][H] bf16 sorted
    const unsigned short* __restrict__ W2t,   // [E][D][H] bf16
    const float* __restrict__ b2,
    const int* __restrict__ offsets,
    const int* __restrict__ toksort,
    const float* __restrict__ topw,
    float* __restrict__ out) {

    __shared__ __align__(16) unsigned short As[128 * 32];
    __shared__ __align__(16) unsigned short Bs[128 * 32];

    int row0, rows;
    int e = find_tile(offsets, blockIdx.x, row0, rows);
    if (e < 0) return;
    int n0 = blockIdx.y << 7;

    int tid = threadIdx.x, l = tid & 63, w = tid >> 6;
    int wm = w & 1, wn = w >> 1;
    int lrow = l & 15, lq = l >> 4;

    floatx4 acc[4][4];
#pragma unroll
    for (int mi = 0; mi < 4; mi++)
#pragma unroll
        for (int ni = 0; ni < 4; ni++) acc[mi][ni] = floatx4{0.f, 0.f, 0.f, 0.f};

    gemm128_bk32<H_DIM>(hb, W2t + (size_t)e * D_DIM * H_DIM,
                        row0, n0, As, Bs, acc);

    float bias[4];
#pragma unroll
    for (int ni = 0; ni < 4; ni++)
        bias[ni] = b2[e * D_DIM + n0 + (wn << 6) + (ni << 4) + lrow];

    // direct f32 stores: 16-lane groups write 64B runs; WRITE already ideal
#pragma unroll
    for (int mi = 0; mi < 4; mi++) {
#pragma unroll
        for (int r = 0; r < 4; r++) {
            int row = (wm << 6) + (mi << 4) + (lq << 2) + r;
            if (row < rows) {
                int p = row0 + row;
                int tok = toksort[p];
                float tw = topw[tok];
#pragma unroll
                for (int ni = 0; ni < 4; ni++) {
                    int d = n0 + (wn << 6) + (ni << 4) + lrow;
                    out[(size_t)tok * D_DIM + d] = tw * (acc[mi][ni][r] + bias[ni]);
                }
            }
        }
    }
}

// ---------------------------------------------------------------------------
// scalar fallback FFN — used only if ws too small
// ---------------------------------------------------------------------------
__global__ __launch_bounds__(FFN_BLK, 2) void moe_ffn_kernel(
    const float* __restrict__ x,
    const float* __restrict__ W1, const float* __restrict__ b1,
    const float* __restrict__ W2, const float* __restrict__ b2,
    const int* __restrict__ offsets,
    const int* __restrict__ toksort,
    const float* __restrict__ topw,
    float* __restrict__ out) {

    __shared__ __align__(16) unsigned short h1c[MT * 1024];
    float* xs = (float*)h1c;

    int bid = blockIdx.x;
    int e = -1, row0 = 0, rows = 0, cum = 0;
    for (int ee = 0; ee < E_NUM; ee++) {
        int o0 = offsets[ee], o1 = offsets[ee + 1];
        int tiles = (o1 - o0 + MT - 1) / MT;
        if (bid < cum + tiles) {
            e = ee;
            row0 = o0 + (bid - cum) * MT;
            rows = (o1 - row0 < MT) ? (o1 - row0) : MT;
            break;
        }
        cum += tiles;
    }
    if (e < 0) return;

    int tid = threadIdx.x;
    const float* W1e = W1 + (size_t)e * D_DIM * H_DIM;
    const float* W2e = W2 + (size_t)e * H_DIM * D_DIM;

    int m_st = tid >> 4;
    int j_st = tid & 15;
    int m_cl = (m_st < rows) ? m_st : (rows - 1);
    int tok_st = toksort[row0 + m_cl];

    float acc2x[MT], acc2y[MT];
#pragma unroll
    for (int m = 0; m < MT; m++) { acc2x[m] = 0.f; acc2y[m] = 0.f; }

    int d0 = tid * 2;

    for (int half = 0; half < 2; half++) {
        int ha = half * 1024 + tid;
        int hb_ = ha + 512;

        float a1a[MT], a1b[MT];
#pragma unroll
        for (int m = 0; m < MT; m++) { a1a[m] = 0.f; a1b[m] = 0.f; }

        for (int dc = 0; dc < 8; dc++) {
            __syncthreads();
            {
                const float4* src =
                    (const float4*)(x + (size_t)tok_st * D_DIM + dc * 128 + j_st * 8);
                float4 v0 = src[0], v1 = src[1];
                float4* dst = (float4*)(xs + m_st * 128 + j_st * 8);
                dst[0] = v0; dst[1] = v1;
            }
            __syncthreads();
            const float* w1pa = W1e + (size_t)(dc * 128) * H_DIM + ha;
            const float* w1pb = W1e + (size_t)(dc * 128) * H_DIM + hb_;
            for (int d2 = 0; d2 < 64; d2++) {
                float wa0 = w1pa[0], wa1 = w1pa[H_DIM];
                float wb0 = w1pb[0], wb1 = w1pb[H_DIM];
                w1pa += 2 * H_DIM; w1pb += 2 * H_DIM;
#pragma unroll
                for (int m = 0; m < MT; m++) {
                    float2 xv = *(const float2*)(xs + m * 128 + d2 * 2);
                    a1a[m] += xv.x * wa0; a1a[m] += xv.y * wa1;
                    a1b[m] += xv.x * wb0; a1b[m] += xv.y * wb1;
                }
            }
        }

        float bba = b1[e * H_DIM + ha];
        float bbb = b1[e * H_DIM + hb_];
        __syncthreads();
#pragma unroll
        for (int m = 0; m < MT; m++) {
            float va = a1a[m] + bba; va = va > 0.f ? va : 0.f;
            float vb = a1b[m] + bbb; vb = vb > 0.f ? vb : 0.f;
            h1c[m * 1024 + tid]       = f2bf_bits(va);
            h1c[m * 1024 + 512 + tid] = f2bf_bits(vb);
        }
        __syncthreads();

        const float* w2p = W2e + (size_t)(half * 1024) * D_DIM + d0;
        for (int hh = 0; hh < 1024; hh += 2) {
            float2 w2a = *(const float2*)(w2p);
            float2 w2b = *(const float2*)(w2p + D_DIM);
            w2p += 2 * D_DIM;
#pragma unroll
            for (int m = 0; m < MT; m++) {
                unsigned int u = *(const unsigned int*)(h1c + m * 1024 + hh);
                float h0  = __uint_as_float(u << 16);
                float h1v = __uint_as_float(u & 0xffff0000u);
                acc2x[m] += h0 * w2a.x; acc2x[m] += h1v * w2b.x;
                acc2y[m] += h0 * w2a.y; acc2y[m] += h1v * w2b.y;
            }
        }
    }

    float bb0 = b2[e * D_DIM + d0];
    float bb1 = b2[e * D_DIM + d0 + 1];
#pragma unroll
    for (int m = 0; m < MT; m++) {
        if (m < rows) {
            int tok  = toksort[row0 + m];
            float tw = topw[tok];
            float2 o;
            o.x = tw * (acc2x[m] + bb0);
            o.y = tw * (acc2y[m] + bb1);
            *(float2*)(out + (size_t)tok * D_DIM + d0) = o;
        }
    }
}

// ---------------------------------------------------------------------------
extern "C" void kernel_launch(void* const* d_in, const int* in_sizes, int n_in,
                              void* d_out, int out_size, void* d_ws, size_t ws_size,
                              hipStream_t stream) {
    const float* x  = (const float*)d_in[0];
    const float* Wg = (const float*)d_in[1];
    const float* bg = (const float*)d_in[2];
    const float* W1 = (const float*)d_in[3];
    const float* b1 = (const float*)d_in[4];
    const float* W2 = (const float*)d_in[5];
    const float* b2 = (const float*)d_in[6];

    float* out = (float*)d_out;
    float* gw  = out + (size_t)N_TOK * D_DIM;

    char* ws = (char*)d_ws;
    int*   counts  = (int*)ws;            // 8 (unused, layout kept)
    int*   cursor  = counts + 8;          // 8
    int*   offsets = cursor + 8;          // 9
    int*   topidx  = (int*)(ws + 128);
    float* topw    = (float*)(ws + 128 + 4 * (size_t)N_TOK);
    int*   toksort = (int*)(ws + 128 + 8 * (size_t)N_TOK);

    const size_t off_xs  = 256ull << 10;
    const size_t off_w1t = off_xs  + (32ull << 20);
    const size_t off_w2t = off_w1t + (32ull << 20);
    const size_t off_hb  = off_w2t + (32ull << 20);
    const size_t need    = off_hb  + (64ull << 20);

    if (ws_size >= need) {
        unsigned short* xs  = (unsigned short*)(ws + off_xs);
        unsigned short* W1t = (unsigned short*)(ws + off_w1t);
        unsigned short* W2t = (unsigned short*)(ws + off_w2t);
        unsigned short* hb  = (unsigned short*)(ws + off_hb);

        moe_gate_transpose_fused<<<12288, 256, 0, stream>>>(
            x, Wg, bg, gw, topw, topidx, W1, W2, W1t, W2t);
        moe_hist_scan_kernel<<<1, 256, 0, stream>>>(topidx, offsets, cursor);
        moe_scatter_gather<<<N_TOK / 64, 256, 0, stream>>>(
            x, topidx, cursor, toksort, xs);

        moe_ffn1_mfma<<<dim3(N_TOK / 128 + E_NUM, H_DIM / 128), 256, 0, stream>>>(
            xs, W1t, b1, offsets, hb);
        moe_ffn2_mfma<<<dim3(N_TOK / 128 + E_NUM, D_DIM / 128), 256, 0, stream>>>(
            hb, W2t, b2, offsets, toksort, topw, out);
    } else {
        moe_gate_kernel<<<N_TOK / 4, 256, 0, stream>>>(
            x, Wg, bg, gw, topw, topidx);
        moe_hist_scan_kernel<<<1, 256, 0, stream>>>(topidx, offsets, cursor);
        moe_scatter_kernel<<<N_TOK / 256, 256, 0, stream>>>(topidx, cursor, toksort);
        moe_ffn_kernel<<<N_TOK / MT + E_NUM, FFN_BLK, 0, stream>>>(
            x, W1, b1, W2, b2, offsets, toksort, topw, out);
    }
}

// Round 9
// 545.187 us; speedup vs baseline: 1.0092x; 1.0092x over previous
//
#include <hip/hip_runtime.h>
#include <hip/hip_bf16.h>

#define N_TOK 16384
#define D_DIM 1024
#define E_NUM 8
#define H_DIM 2048
#define MT 32          // tokens per scalar-fallback FFN tile
#define FFN_BLK 512

typedef __attribute__((ext_vector_type(8))) short short8;
typedef __attribute__((ext_vector_type(4))) float floatx4;

__device__ __forceinline__ unsigned short f2bf_bits(float f) {
    __hip_bfloat16 h = __float2bfloat16(f);   // RNE
    return *reinterpret_cast<unsigned short*>(&h);
}

// async global->LDS, 16B per lane; LDS dest = wave-uniform base + lane*16
__device__ __forceinline__ void async16(const void* g, void* l) {
    __builtin_amdgcn_global_load_lds(
        (const __attribute__((address_space(1))) unsigned int*)g,
        (__attribute__((address_space(3))) unsigned int*)l,
        16, 0, 0);
}

// ---------------------------------------------------------------------------
// K1: fused gate + weight transpose-cast (independent work, one launch).
// blocks [0,8192): W1/W2 transpose+cast. blocks [8192,12288): gating.
// ---------------------------------------------------------------------------
__global__ __launch_bounds__(256) void moe_gate_transpose_fused(
    const float* __restrict__ x,
    const float* __restrict__ Wg,
    const float* __restrict__ bg,
    float* __restrict__ gw_out,
    float* __restrict__ topw,
    int* __restrict__ topidx,
    const float* __restrict__ W1,
    const float* __restrict__ W2,
    unsigned short* __restrict__ W1t,
    unsigned short* __restrict__ W2t) {

    __shared__ float tile[64][65];

    if (blockIdx.x < 8192) {
        // ---- transpose branch ----
        int id = blockIdx.x;
        const float* in; unsigned short* out; int R, C, cx, ry, e;
        if (id < 4096) {
            e = id >> 9; int t = id & 511;
            in = W1; out = W1t; R = 1024; C = 2048;
            cx = t & 31; ry = t >> 5;
        } else {
            id -= 4096;
            e = id >> 9; int t = id & 511;
            in = W2; out = W2t; R = 2048; C = 1024;
            cx = t & 15; ry = t >> 4;
        }
        const float* inE = in + (size_t)e * 2097152;
        unsigned short* outE = out + (size_t)e * 2097152;
        int c0 = cx << 6, r0 = ry << 6;
        int tr = threadIdx.x >> 4;
        int tc = (threadIdx.x & 15) << 2;
#pragma unroll
        for (int i = 0; i < 4; i++) {
            int r = tr + (i << 4);
            float4 v = *(const float4*)(inE + (size_t)(r0 + r) * C + c0 + tc);
            tile[r][tc + 0] = v.x; tile[r][tc + 1] = v.y;
            tile[r][tc + 2] = v.z; tile[r][tc + 3] = v.w;
        }
        __syncthreads();
#pragma unroll
        for (int it = 0; it < 2; it++) {
            int task = threadIdx.x + (it << 8);
            int c = task >> 3, rr = (task & 7) << 3;
            short8 o;
#pragma unroll
            for (int j = 0; j < 8; j++)
                ((unsigned short*)&o)[j] = f2bf_bits(tile[rr + j][c]);
            *(short8*)(outE + (size_t)(c0 + c) * R + r0 + rr) = o;
        }
        return;
    }

    // ---- gate branch: one wave per token ----
    int bid = blockIdx.x - 8192;
    int wave = ((bid << 8) + threadIdx.x) >> 6;
    int lane = threadIdx.x & 63;
    if (wave >= N_TOK) return;
    const float* xr = x + (size_t)wave * D_DIM;

    float4 xv[4];
#pragma unroll
    for (int i = 0; i < 4; i++)
        xv[i] = *(const float4*)(xr + i * 256 + lane * 4);

    float acc[8];
#pragma unroll
    for (int e = 0; e < 8; e++) acc[e] = 0.f;

#pragma unroll
    for (int i = 0; i < 4; i++) {
        const float xs4[4] = {xv[i].x, xv[i].y, xv[i].z, xv[i].w};
        const float* wp = Wg + ((size_t)(i * 256) + lane * 4) * 8;
#pragma unroll
        for (int j = 0; j < 4; j++) {
            float4 w0 = *(const float4*)(wp + j * 8);
            float4 w1 = *(const float4*)(wp + j * 8 + 4);
            float s = xs4[j];
            acc[0] += s * w0.x; acc[1] += s * w0.y;
            acc[2] += s * w0.z; acc[3] += s * w0.w;
            acc[4] += s * w1.x; acc[5] += s * w1.y;
            acc[6] += s * w1.z; acc[7] += s * w1.w;
        }
    }
#pragma unroll
    for (int e = 0; e < 8; e++) {
#pragma unroll
        for (int off = 32; off > 0; off >>= 1)
            acc[e] += __shfl_xor(acc[e], off, 64);
    }
#pragma unroll
    for (int e = 0; e < 8; e++) acc[e] += bg[e];

    float mx = acc[0]; int am = 0;
#pragma unroll
    for (int e = 1; e < 8; e++) { if (acc[e] > mx) { mx = acc[e]; am = e; } }
    float w[8], s = 0.f;
#pragma unroll
    for (int e = 0; e < 8; e++) { w[e] = expf(acc[e] - mx); s += w[e]; }
    float inv = 1.f / s;
#pragma unroll
    for (int e = 0; e < 8; e++) w[e] *= inv;

    if (lane == 0) {
        float4 a = make_float4(w[0], w[1], w[2], w[3]);
        float4 b = make_float4(w[4], w[5], w[6], w[7]);
        *(float4*)(gw_out + (size_t)wave * 8)     = a;
        *(float4*)(gw_out + (size_t)wave * 8 + 4) = b;
        topw[wave]   = w[am];
        topidx[wave] = am;
    }
}

// standalone gate for the fallback path
__global__ __launch_bounds__(256) void moe_gate_kernel(
    const float* __restrict__ x,
    const float* __restrict__ Wg,
    const float* __restrict__ bg,
    float* __restrict__ gw_out,
    float* __restrict__ topw,
    int* __restrict__ topidx) {
    int wave = (blockIdx.x * blockDim.x + threadIdx.x) >> 6;
    int lane = threadIdx.x & 63;
    if (wave >= N_TOK) return;
    const float* xr = x + (size_t)wave * D_DIM;

    float4 xv[4];
#pragma unroll
    for (int i = 0; i < 4; i++)
        xv[i] = *(const float4*)(xr + i * 256 + lane * 4);

    float acc[8];
#pragma unroll
    for (int e = 0; e < 8; e++) acc[e] = 0.f;
#pragma unroll
    for (int i = 0; i < 4; i++) {
        const float xs4[4] = {xv[i].x, xv[i].y, xv[i].z, xv[i].w};
        const float* wp = Wg + ((size_t)(i * 256) + lane * 4) * 8;
#pragma unroll
        for (int j = 0; j < 4; j++) {
            float4 w0 = *(const float4*)(wp + j * 8);
            float4 w1 = *(const float4*)(wp + j * 8 + 4);
            float s = xs4[j];
            acc[0] += s * w0.x; acc[1] += s * w0.y;
            acc[2] += s * w0.z; acc[3] += s * w0.w;
            acc[4] += s * w1.x; acc[5] += s * w1.y;
            acc[6] += s * w1.z; acc[7] += s * w1.w;
        }
    }
#pragma unroll
    for (int e = 0; e < 8; e++) {
#pragma unroll
        for (int off = 32; off > 0; off >>= 1)
            acc[e] += __shfl_xor(acc[e], off, 64);
    }
#pragma unroll
    for (int e = 0; e < 8; e++) acc[e] += bg[e];

    float mx = acc[0]; int am = 0;
#pragma unroll
    for (int e = 1; e < 8; e++) { if (acc[e] > mx) { mx = acc[e]; am = e; } }
    float w[8], s = 0.f;
#pragma unroll
    for (int e = 0; e < 8; e++) { w[e] = expf(acc[e] - mx); s += w[e]; }
    float inv = 1.f / s;
#pragma unroll
    for (int e = 0; e < 8; e++) w[e] *= inv;

    if (lane == 0) {
        float4 a = make_float4(w[0], w[1], w[2], w[3]);
        float4 b = make_float4(w[4], w[5], w[6], w[7]);
        *(float4*)(gw_out + (size_t)wave * 8)     = a;
        *(float4*)(gw_out + (size_t)wave * 8 + 4) = b;
        topw[wave]   = w[am];
        topidx[wave] = am;
    }
}

// K2: single-block histogram+scan, int4 loads
__global__ __launch_bounds__(256) void moe_hist_scan_kernel(
    const int* __restrict__ topidx,
    int* __restrict__ offsets,
    int* __restrict__ cursor) {
    __shared__ int part[256][8];
    int tid = threadIdx.x;
    int c0 = 0, c1 = 0, c2 = 0, c3 = 0, c4 = 0, c5 = 0, c6 = 0, c7 = 0;
    const int4* tp = (const int4*)topidx;
    for (int i = 0; i < N_TOK / 1024; i++) {
        int4 v = tp[tid + (i << 8)];
#pragma unroll
        for (int j = 0; j < 4; j++) {
            int idx = (&v.x)[j];
            c0 += (idx == 0); c1 += (idx == 1); c2 += (idx == 2); c3 += (idx == 3);
            c4 += (idx == 4); c5 += (idx == 5); c6 += (idx == 6); c7 += (idx == 7);
        }
    }
    part[tid][0] = c0; part[tid][1] = c1; part[tid][2] = c2; part[tid][3] = c3;
    part[tid][4] = c4; part[tid][5] = c5; part[tid][6] = c6; part[tid][7] = c7;
    __syncthreads();
    for (int s = 128; s > 0; s >>= 1) {
        if (tid < s) {
#pragma unroll
            for (int e = 0; e < 8; e++) part[tid][e] += part[tid + s][e];
        }
        __syncthreads();
    }
    if (tid == 0) {
        int run = 0;
        for (int e = 0; e < 8; e++) {
            offsets[e] = run;
            cursor[e]  = run;
            run += part[0][e];
        }
        offsets[8] = run;
    }
}

// K3: scatter + cast + gather fused. Block owns 64 tokens; LDS-atomic local
// rank + 8 global atomics, then xs[p] = bf16(x[t]). ffn1 reads SORTED xs.
__global__ __launch_bounds__(256) void moe_scatter_gather(
    const float* __restrict__ x,
    const int* __restrict__ topidx,
    int* __restrict__ cursor,
    int* __restrict__ toksort,
    unsigned short* __restrict__ xs) {
    __shared__ int lcnt[8];
    __shared__ int lbase[8];
    __shared__ int s_pos[64];
    int tid = threadIdx.x;
    int base = blockIdx.x << 6;
    if (tid < 8) lcnt[tid] = 0;
    __syncthreads();
    int e = 0, r = 0;
    if (tid < 64) {
        e = topidx[base + tid];
        r = atomicAdd(&lcnt[e], 1);   // LDS atomic
    }
    __syncthreads();
    if (tid < 8) lbase[tid] = atomicAdd(&cursor[tid], lcnt[tid]);
    __syncthreads();
    if (tid < 64) {
        int p = lbase[e] + r;
        toksort[p] = base + tid;
        s_pos[tid] = p;
    }
    __syncthreads();
    for (int rr = 0; rr < 64; rr++) {
        int tok = base + rr;
        int p = s_pos[rr];
        float4 v = *(const float4*)(x + (size_t)tok * D_DIM + (tid << 2));
        ushort4 o;
        o.x = f2bf_bits(v.x); o.y = f2bf_bits(v.y);
        o.z = f2bf_bits(v.z); o.w = f2bf_bits(v.w);
        *(ushort4*)(xs + (size_t)p * D_DIM + (tid << 2)) = o;
    }
}

// fallback scatter (no xs buffer)
__global__ __launch_bounds__(256) void moe_scatter_kernel(
    const int* __restrict__ topidx,
    int* __restrict__ cursor,
    int* __restrict__ toksort) {
    __shared__ int lcnt[8];
    __shared__ int lbase[8];
    int tid = threadIdx.x;
    int t = blockIdx.x * blockDim.x + tid;
    if (tid < 8) lcnt[tid] = 0;
    __syncthreads();
    int e = topidx[t];
    int r = atomicAdd(&lcnt[e], 1);
    __syncthreads();
    if (tid < 8) lbase[tid] = atomicAdd(&cursor[tid], lcnt[tid]);
    __syncthreads();
    toksort[lbase[e] + r] = t;
}

// ---------------------------------------------------------------------------
// MFMA GEMMs: EXACT round-1 kernels (best measured: ffn1 130 / ffn2 ~125).
// 128x128 tile, BK=32, 16KB LDS (separate As/Bs), 4 waves 2x2, 4x4 frags.
// Session evidence ledger (all A/B'd against this core):
//   +XCD swizzle        -> -14us  (r4; L3-resident regime)
//   BK=64               -> -17us  (r5; occupancy loss > barrier savings)
//   granule swizzle     ->  0     (r5/r6; conflicts non-binding)
//   toksort-gather      -> -21us  (r6; scattered staging kills L2)
//   repack epilogue     -> -17us  (r7; WRITE amplification non-binding,
//                                  extra barriers/half-idle waves cost)
// -> the unmodified r1 kernel is the measured optimum of this family.
// frag A: lane l -> A[m=l&15][k=(l>>4)*8+j]; frag B: B[k=(l>>4)*8+j][n=l&15]
// C/D:   row=(l>>4)*4+r, col=l&15   (HW-verified layouts)
// ---------------------------------------------------------------------------
__device__ __forceinline__ int find_tile(const int* offsets, int mt,
                                         int& row0, int& rows) {
    int cum = 0;
    for (int ee = 0; ee < E_NUM; ee++) {
        int o0 = offsets[ee], o1 = offsets[ee + 1];
        int tiles = (o1 - o0 + 127) >> 7;
        if (mt < cum + tiles) {
            row0 = o0 + ((mt - cum) << 7);
            rows = o1 - row0; if (rows > 128) rows = 128;
            return ee;
        }
        cum += tiles;
    }
    return -1;
}

__global__ __launch_bounds__(256) void moe_ffn1_mfma(
    const unsigned short* __restrict__ xs,    // [N][D] bf16 SORTED order
    const unsigned short* __restrict__ W1t,   // [E][H][D] bf16
    const float* __restrict__ b1,
    const int* __restrict__ offsets,
    unsigned short* __restrict__ hb) {        // [N][H] bf16, sorted order

    __shared__ __align__(16) unsigned short As[128 * 32];
    __shared__ __align__(16) unsigned short Bs[128 * 32];

    int row0, rows;
    int e = find_tile(offsets, blockIdx.x, row0, rows);
    if (e < 0) return;
    int n0 = blockIdx.y << 7;

    int tid = threadIdx.x, l = tid & 63, w = tid >> 6;
    int wm = w & 1, wn = w >> 1;
    int lrow = l & 15, lq = l >> 4;
    const unsigned short* Be = W1t + (size_t)e * H_DIM * D_DIM;

    floatx4 acc[4][4];
#pragma unroll
    for (int mi = 0; mi < 4; mi++)
#pragma unroll
        for (int ni = 0; ni < 4; ni++) acc[mi][ni] = floatx4{0.f, 0.f, 0.f, 0.f};

    int srow = (w << 5) + (l >> 2);   // staging row (+0/+16)
    int koff = (l & 3) << 3;          // k offset in ushorts

    for (int kt = 0; kt < D_DIM / 32; kt++) {
        int kb = kt << 5;
        __syncthreads();
#pragma unroll
        for (int i = 0; i < 2; i++) {
            int r = srow + (i << 4);
            int p = row0 + r; if (p > N_TOK - 1) p = N_TOK - 1;
            async16(xs + (size_t)p * D_DIM + kb + koff,
                    As + (((w << 5) + (i << 4)) << 5));
            async16(Be + (size_t)(n0 + r) * D_DIM + kb + koff,
                    Bs + (((w << 5) + (i << 4)) << 5));
        }
        __syncthreads();
        short8 af[4], bfv[4];
#pragma unroll
        for (int mi = 0; mi < 4; mi++)
            af[mi] = *(const short8*)(As + (((wm << 6) + (mi << 4) + lrow) << 5) + (lq << 3));
#pragma unroll
        for (int ni = 0; ni < 4; ni++)
            bfv[ni] = *(const short8*)(Bs + (((wn << 6) + (ni << 4) + lrow) << 5) + (lq << 3));
#pragma unroll
        for (int mi = 0; mi < 4; mi++)
#pragma unroll
            for (int ni = 0; ni < 4; ni++)
                acc[mi][ni] = __builtin_amdgcn_mfma_f32_16x16x32_bf16(
                    af[mi], bfv[ni], acc[mi][ni], 0, 0, 0);
    }

#pragma unroll
    for (int ni = 0; ni < 4; ni++) {
        int h = n0 + (wn << 6) + (ni << 4) + lrow;
        float bias = b1[e * H_DIM + h];
#pragma unroll
        for (int mi = 0; mi < 4; mi++) {
#pragma unroll
            for (int r = 0; r < 4; r++) {
                int row = (wm << 6) + (mi << 4) + (lq << 2) + r;
                if (row < rows) {
                    float v = acc[mi][ni][r] + bias;
                    v = v > 0.f ? v : 0.f;
                    hb[(size_t)(row0 + row) * H_DIM + h] = f2bf_bits(v);
                }
            }
        }
    }
}

__global__ __launch_bounds__(256) void moe_ffn2_mfma(
    const unsigned short* __restrict__ hb,    // [N][H] bf16 sorted
    const unsigned short* __restrict__ W2t,   // [E][D][H] bf16
    const float* __restrict__ b2,
    const int* __restrict__ offsets,
    const int* __restrict__ toksort,
    const float* __restrict__ topw,
    float* __restrict__ out) {

    __shared__ __align__(16) unsigned short As[128 * 32];
    __shared__ __align__(16) unsigned short Bs[128 * 32];

    int row0, rows;
    int e = find_tile(offsets, blockIdx.x, row0, rows);
    if (e < 0) return;
    int n0 = blockIdx.y << 7;

    int tid = threadIdx.x, l = tid & 63, w = tid >> 6;
    int wm = w & 1, wn = w >> 1;
    int lrow = l & 15, lq = l >> 4;
    const unsigned short* Be = W2t + (size_t)e * D_DIM * H_DIM;

    floatx4 acc[4][4];
#pragma unroll
    for (int mi = 0; mi < 4; mi++)
#pragma unroll
        for (int ni = 0; ni < 4; ni++) acc[mi][ni] = floatx4{0.f, 0.f, 0.f, 0.f};

    int srow = (w << 5) + (l >> 2);
    int koff = (l & 3) << 3;

    for (int kt = 0; kt < H_DIM / 32; kt++) {
        int kb = kt << 5;
        __syncthreads();
#pragma unroll
        for (int i = 0; i < 2; i++) {
            int r = srow + (i << 4);
            int p = row0 + r; if (p > N_TOK - 1) p = N_TOK - 1;
            async16(hb + (size_t)p * H_DIM + kb + koff,
                    As + (((w << 5) + (i << 4)) << 5));
            async16(Be + (size_t)(n0 + r) * H_DIM + kb + koff,
                    Bs + (((w << 5) + (i << 4)) << 5));
        }
        __syncthreads();
        short8 af[4], bfv[4];
#pragma unroll
        for (int mi = 0; mi < 4; mi++)
            af[mi] = *(const short8*)(As + (((wm << 6) + (mi << 4) + lrow) << 5) + (lq << 3));
#pragma unroll
        for (int ni = 0; ni < 4; ni++)
            bfv[ni] = *(const short8*)(Bs + (((wn << 6) + (ni << 4) + lrow) << 5) + (lq << 3));
#pragma unroll
        for (int mi = 0; mi < 4; mi++)
#pragma unroll
            for (int ni = 0; ni < 4; ni++)
                acc[mi][ni] = __builtin_amdgcn_mfma_f32_16x16x32_bf16(
                    af[mi], bfv[ni], acc[mi][ni], 0, 0, 0);
    }

    float bias[4];
#pragma unroll
    for (int ni = 0; ni < 4; ni++)
        bias[ni] = b2[e * D_DIM + n0 + (wn << 6) + (ni << 4) + lrow];

#pragma unroll
    for (int mi = 0; mi < 4; mi++) {
#pragma unroll
        for (int r = 0; r < 4; r++) {
            int row = (wm << 6) + (mi << 4) + (lq << 2) + r;
            if (row < rows) {
                int p = row0 + row;
                int tok = toksort[p];
                float tw = topw[tok];
#pragma unroll
                for (int ni = 0; ni < 4; ni++) {
                    int d = n0 + (wn << 6) + (ni << 4) + lrow;
                    out[(size_t)tok * D_DIM + d] = tw * (acc[mi][ni][r] + bias[ni]);
                }
            }
        }
    }
}

// ---------------------------------------------------------------------------
// scalar fallback FFN — used only if ws too small
// ---------------------------------------------------------------------------
__global__ __launch_bounds__(FFN_BLK, 2) void moe_ffn_kernel(
    const float* __restrict__ x,
    const float* __restrict__ W1, const float* __restrict__ b1,
    const float* __restrict__ W2, const float* __restrict__ b2,
    const int* __restrict__ offsets,
    const int* __restrict__ toksort,
    const float* __restrict__ topw,
    float* __restrict__ out) {

    __shared__ __align__(16) unsigned short h1c[MT * 1024];
    float* xs = (float*)h1c;

    int bid = blockIdx.x;
    int e = -1, row0 = 0, rows = 0, cum = 0;
    for (int ee = 0; ee < E_NUM; ee++) {
        int o0 = offsets[ee], o1 = offsets[ee + 1];
        int tiles = (o1 - o0 + MT - 1) / MT;
        if (bid < cum + tiles) {
            e = ee;
            row0 = o0 + (bid - cum) * MT;
            rows = (o1 - row0 < MT) ? (o1 - row0) : MT;
            break;
        }
        cum += tiles;
    }
    if (e < 0) return;

    int tid = threadIdx.x;
    const float* W1e = W1 + (size_t)e * D_DIM * H_DIM;
    const float* W2e = W2 + (size_t)e * H_DIM * D_DIM;

    int m_st = tid >> 4;
    int j_st = tid & 15;
    int m_cl = (m_st < rows) ? m_st : (rows - 1);
    int tok_st = toksort[row0 + m_cl];

    float acc2x[MT], acc2y[MT];
#pragma unroll
    for (int m = 0; m < MT; m++) { acc2x[m] = 0.f; acc2y[m] = 0.f; }

    int d0 = tid * 2;

    for (int half = 0; half < 2; half++) {
        int ha = half * 1024 + tid;
        int hb_ = ha + 512;

        float a1a[MT], a1b[MT];
#pragma unroll
        for (int m = 0; m < MT; m++) { a1a[m] = 0.f; a1b[m] = 0.f; }

        for (int dc = 0; dc < 8; dc++) {
            __syncthreads();
            {
                const float4* src =
                    (const float4*)(x + (size_t)tok_st * D_DIM + dc * 128 + j_st * 8);
                float4 v0 = src[0], v1 = src[1];
                float4* dst = (float4*)(xs + m_st * 128 + j_st * 8);
                dst[0] = v0; dst[1] = v1;
            }
            __syncthreads();
            const float* w1pa = W1e + (size_t)(dc * 128) * H_DIM + ha;
            const float* w1pb = W1e + (size_t)(dc * 128) * H_DIM + hb_;
            for (int d2 = 0; d2 < 64; d2++) {
                float wa0 = w1pa[0], wa1 = w1pa[H_DIM];
                float wb0 = w1pb[0], wb1 = w1pb[H_DIM];
                w1pa += 2 * H_DIM; w1pb += 2 * H_DIM;
#pragma unroll
                for (int m = 0; m < MT; m++) {
                    float2 xv = *(const float2*)(xs + m * 128 + d2 * 2);
                    a1a[m] += xv.x * wa0; a1a[m] += xv.y * wa1;
                    a1b[m] += xv.x * wb0; a1b[m] += xv.y * wb1;
                }
            }
        }

        float bba = b1[e * H_DIM + ha];
        float bbb = b1[e * H_DIM + hb_];
        __syncthreads();
#pragma unroll
        for (int m = 0; m < MT; m++) {
            float va = a1a[m] + bba; va = va > 0.f ? va : 0.f;
            float vb = a1b[m] + bbb; vb = vb > 0.f ? vb : 0.f;
            h1c[m * 1024 + tid]       = f2bf_bits(va);
            h1c[m * 1024 + 512 + tid] = f2bf_bits(vb);
        }
        __syncthreads();

        const float* w2p = W2e + (size_t)(half * 1024) * D_DIM + d0;
        for (int hh = 0; hh < 1024; hh += 2) {
            float2 w2a = *(const float2*)(w2p);
            float2 w2b = *(const float2*)(w2p + D_DIM);
            w2p += 2 * D_DIM;
#pragma unroll
            for (int m = 0; m < MT; m++) {
                unsigned int u = *(const unsigned int*)(h1c + m * 1024 + hh);
                float h0  = __uint_as_float(u << 16);
                float h1v = __uint_as_float(u & 0xffff0000u);
                acc2x[m] += h0 * w2a.x; acc2x[m] += h1v * w2b.x;
                acc2y[m] += h0 * w2a.y; acc2y[m] += h1v * w2b.y;
            }
        }
    }

    float bb0 = b2[e * D_DIM + d0];
    float bb1 = b2[e * D_DIM + d0 + 1];
#pragma unroll
    for (int m = 0; m < MT; m++) {
        if (m < rows) {
            int tok  = toksort[row0 + m];
            float tw = topw[tok];
            float2 o;
            o.x = tw * (acc2x[m] + bb0);
            o.y = tw * (acc2y[m] + bb1);
            *(float2*)(out + (size_t)tok * D_DIM + d0) = o;
        }
    }
}

// ---------------------------------------------------------------------------
extern "C" void kernel_launch(void* const* d_in, const int* in_sizes, int n_in,
                              void* d_out, int out_size, void* d_ws, size_t ws_size,
                              hipStream_t stream) {
    const float* x  = (const float*)d_in[0];
    const float* Wg = (const float*)d_in[1];
    const float* bg = (const float*)d_in[2];
    const float* W1 = (const float*)d_in[3];
    const float* b1 = (const float*)d_in[4];
    const float* W2 = (const float*)d_in[5];
    const float* b2 = (const float*)d_in[6];

    float* out = (float*)d_out;
    float* gw  = out + (size_t)N_TOK * D_DIM;

    char* ws = (char*)d_ws;
    int*   counts  = (int*)ws;            // 8 (unused, layout kept)
    int*   cursor  = counts + 8;          // 8
    int*   offsets = cursor + 8;          // 9
    int*   topidx  = (int*)(ws + 128);
    float* topw    = (float*)(ws + 128 + 4 * (size_t)N_TOK);
    int*   toksort = (int*)(ws + 128 + 8 * (size_t)N_TOK);

    const size_t off_xs  = 256ull << 10;
    const size_t off_w1t = off_xs  + (32ull << 20);
    const size_t off_w2t = off_w1t + (32ull << 20);
    const size_t off_hb  = off_w2t + (32ull << 20);
    const size_t need    = off_hb  + (64ull << 20);

    if (ws_size >= need) {
        unsigned short* xs  = (unsigned short*)(ws + off_xs);
        unsigned short* W1t = (unsigned short*)(ws + off_w1t);
        unsigned short* W2t = (unsigned short*)(ws + off_w2t);
        unsigned short* hb  = (unsigned short*)(ws + off_hb);

        moe_gate_transpose_fused<<<12288, 256, 0, stream>>>(
            x, Wg, bg, gw, topw, topidx, W1, W2, W1t, W2t);
        moe_hist_scan_kernel<<<1, 256, 0, stream>>>(topidx, offsets, cursor);
        moe_scatter_gather<<<N_TOK / 64, 256, 0, stream>>>(
            x, topidx, cursor, toksort, xs);

        moe_ffn1_mfma<<<dim3(N_TOK / 128 + E_NUM, H_DIM / 128), 256, 0, stream>>>(
            xs, W1t, b1, offsets, hb);
        moe_ffn2_mfma<<<dim3(N_TOK / 128 + E_NUM, D_DIM / 128), 256, 0, stream>>>(
            hb, W2t, b2, offsets, toksort, topw, out);
    } else {
        moe_gate_kernel<<<N_TOK / 4, 256, 0, stream>>>(
            x, Wg, bg, gw, topw, topidx);
        moe_hist_scan_kernel<<<1, 256, 0, stream>>>(topidx, offsets, cursor);
        moe_scatter_kernel<<<N_TOK / 256, 256, 0, stream>>>(topidx, cursor, toksort);
        moe_ffn_kernel<<<N_TOK / MT + E_NUM, FFN_BLK, 0, stream>>>(
            x, W1, b1, W2, b2, offsets, toksort, topw, out);
    }
}

// Round 10
// 527.701 us; speedup vs baseline: 1.0426x; 1.0331x over previous
//
#include <hip/hip_runtime.h>
#include <hip/hip_bf16.h>

#define N_TOK 16384
#define D_DIM 1024
#define E_NUM 8
#define H_DIM 2048
#define MT 32          // tokens per scalar-fallback FFN tile
#define FFN_BLK 512

typedef __attribute__((ext_vector_type(8))) short short8;
typedef __attribute__((ext_vector_type(4))) float floatx4;

__device__ __forceinline__ unsigned short f2bf_bits(float f) {
    __hip_bfloat16 h = __float2bfloat16(f);   // RNE
    return *reinterpret_cast<unsigned short*>(&h);
}

// async global->LDS, 16B per lane; LDS dest = wave-uniform base + lane*16
__device__ __forceinline__ void async16(const void* g, void* l) {
    __builtin_amdgcn_global_load_lds(
        (const __attribute__((address_space(1))) unsigned int*)g,
        (__attribute__((address_space(3))) unsigned int*)l,
        16, 0, 0);
}

// ---------------------------------------------------------------------------
// K1: fused gate + weight transpose-cast (independent work, one launch).
// ---------------------------------------------------------------------------
__global__ __launch_bounds__(256) void moe_gate_transpose_fused(
    const float* __restrict__ x,
    const float* __restrict__ Wg,
    const float* __restrict__ bg,
    float* __restrict__ gw_out,
    float* __restrict__ topw,
    int* __restrict__ topidx,
    const float* __restrict__ W1,
    const float* __restrict__ W2,
    unsigned short* __restrict__ W1t,
    unsigned short* __restrict__ W2t) {

    __shared__ float tile[64][65];

    if (blockIdx.x < 8192) {
        // ---- transpose branch ----
        int id = blockIdx.x;
        const float* in; unsigned short* out; int R, C, cx, ry, e;
        if (id < 4096) {
            e = id >> 9; int t = id & 511;
            in = W1; out = W1t; R = 1024; C = 2048;
            cx = t & 31; ry = t >> 5;
        } else {
            id -= 4096;
            e = id >> 9; int t = id & 511;
            in = W2; out = W2t; R = 2048; C = 1024;
            cx = t & 15; ry = t >> 4;
        }
        const float* inE = in + (size_t)e * 2097152;
        unsigned short* outE = out + (size_t)e * 2097152;
        int c0 = cx << 6, r0 = ry << 6;
        int tr = threadIdx.x >> 4;
        int tc = (threadIdx.x & 15) << 2;
#pragma unroll
        for (int i = 0; i < 4; i++) {
            int r = tr + (i << 4);
            float4 v = *(const float4*)(inE + (size_t)(r0 + r) * C + c0 + tc);
            tile[r][tc + 0] = v.x; tile[r][tc + 1] = v.y;
            tile[r][tc + 2] = v.z; tile[r][tc + 3] = v.w;
        }
        __syncthreads();
#pragma unroll
        for (int it = 0; it < 2; it++) {
            int task = threadIdx.x + (it << 8);
            int c = task >> 3, rr = (task & 7) << 3;
            short8 o;
#pragma unroll
            for (int j = 0; j < 8; j++)
                ((unsigned short*)&o)[j] = f2bf_bits(tile[rr + j][c]);
            *(short8*)(outE + (size_t)(c0 + c) * R + r0 + rr) = o;
        }
        return;
    }

    // ---- gate branch: one wave per token ----
    int bid = blockIdx.x - 8192;
    int wave = ((bid << 8) + threadIdx.x) >> 6;
    int lane = threadIdx.x & 63;
    if (wave >= N_TOK) return;
    const float* xr = x + (size_t)wave * D_DIM;

    float4 xv[4];
#pragma unroll
    for (int i = 0; i < 4; i++)
        xv[i] = *(const float4*)(xr + i * 256 + lane * 4);

    float acc[8];
#pragma unroll
    for (int e = 0; e < 8; e++) acc[e] = 0.f;

#pragma unroll
    for (int i = 0; i < 4; i++) {
        const float xs4[4] = {xv[i].x, xv[i].y, xv[i].z, xv[i].w};
        const float* wp = Wg + ((size_t)(i * 256) + lane * 4) * 8;
#pragma unroll
        for (int j = 0; j < 4; j++) {
            float4 w0 = *(const float4*)(wp + j * 8);
            float4 w1 = *(const float4*)(wp + j * 8 + 4);
            float s = xs4[j];
            acc[0] += s * w0.x; acc[1] += s * w0.y;
            acc[2] += s * w0.z; acc[3] += s * w0.w;
            acc[4] += s * w1.x; acc[5] += s * w1.y;
            acc[6] += s * w1.z; acc[7] += s * w1.w;
        }
    }
#pragma unroll
    for (int e = 0; e < 8; e++) {
#pragma unroll
        for (int off = 32; off > 0; off >>= 1)
            acc[e] += __shfl_xor(acc[e], off, 64);
    }
#pragma unroll
    for (int e = 0; e < 8; e++) acc[e] += bg[e];

    float mx = acc[0]; int am = 0;
#pragma unroll
    for (int e = 1; e < 8; e++) { if (acc[e] > mx) { mx = acc[e]; am = e; } }
    float w[8], s = 0.f;
#pragma unroll
    for (int e = 0; e < 8; e++) { w[e] = expf(acc[e] - mx); s += w[e]; }
    float inv = 1.f / s;
#pragma unroll
    for (int e = 0; e < 8; e++) w[e] *= inv;

    if (lane == 0) {
        float4 a = make_float4(w[0], w[1], w[2], w[3]);
        float4 b = make_float4(w[4], w[5], w[6], w[7]);
        *(float4*)(gw_out + (size_t)wave * 8)     = a;
        *(float4*)(gw_out + (size_t)wave * 8 + 4) = b;
        topw[wave]   = w[am];
        topidx[wave] = am;
    }
}

// standalone gate for the fallback path
__global__ __launch_bounds__(256) void moe_gate_kernel(
    const float* __restrict__ x,
    const float* __restrict__ Wg,
    const float* __restrict__ bg,
    float* __restrict__ gw_out,
    float* __restrict__ topw,
    int* __restrict__ topidx) {
    int wave = (blockIdx.x * blockDim.x + threadIdx.x) >> 6;
    int lane = threadIdx.x & 63;
    if (wave >= N_TOK) return;
    const float* xr = x + (size_t)wave * D_DIM;

    float4 xv[4];
#pragma unroll
    for (int i = 0; i < 4; i++)
        xv[i] = *(const float4*)(xr + i * 256 + lane * 4);

    float acc[8];
#pragma unroll
    for (int e = 0; e < 8; e++) acc[e] = 0.f;
#pragma unroll
    for (int i = 0; i < 4; i++) {
        const float xs4[4] = {xv[i].x, xv[i].y, xv[i].z, xv[i].w};
        const float* wp = Wg + ((size_t)(i * 256) + lane * 4) * 8;
#pragma unroll
        for (int j = 0; j < 4; j++) {
            float4 w0 = *(const float4*)(wp + j * 8);
            float4 w1 = *(const float4*)(wp + j * 8 + 4);
            float s = xs4[j];
            acc[0] += s * w0.x; acc[1] += s * w0.y;
            acc[2] += s * w0.z; acc[3] += s * w0.w;
            acc[4] += s * w1.x; acc[5] += s * w1.y;
            acc[6] += s * w1.z; acc[7] += s * w1.w;
        }
    }
#pragma unroll
    for (int e = 0; e < 8; e++) {
#pragma unroll
        for (int off = 32; off > 0; off >>= 1)
            acc[e] += __shfl_xor(acc[e], off, 64);
    }
#pragma unroll
    for (int e = 0; e < 8; e++) acc[e] += bg[e];

    float mx = acc[0]; int am = 0;
#pragma unroll
    for (int e = 1; e < 8; e++) { if (acc[e] > mx) { mx = acc[e]; am = e; } }
    float w[8], s = 0.f;
#pragma unroll
    for (int e = 0; e < 8; e++) { w[e] = expf(acc[e] - mx); s += w[e]; }
    float inv = 1.f / s;
#pragma unroll
    for (int e = 0; e < 8; e++) w[e] *= inv;

    if (lane == 0) {
        float4 a = make_float4(w[0], w[1], w[2], w[3]);
        float4 b = make_float4(w[4], w[5], w[6], w[7]);
        *(float4*)(gw_out + (size_t)wave * 8)     = a;
        *(float4*)(gw_out + (size_t)wave * 8 + 4) = b;
        topw[wave]   = w[am];
        topidx[wave] = am;
    }
}

// K2: single-block histogram+scan, int4 loads
__global__ __launch_bounds__(256) void moe_hist_scan_kernel(
    const int* __restrict__ topidx,
    int* __restrict__ offsets,
    int* __restrict__ cursor) {
    __shared__ int part[256][8];
    int tid = threadIdx.x;
    int c0 = 0, c1 = 0, c2 = 0, c3 = 0, c4 = 0, c5 = 0, c6 = 0, c7 = 0;
    const int4* tp = (const int4*)topidx;
    for (int i = 0; i < N_TOK / 1024; i++) {
        int4 v = tp[tid + (i << 8)];
#pragma unroll
        for (int j = 0; j < 4; j++) {
            int idx = (&v.x)[j];
            c0 += (idx == 0); c1 += (idx == 1); c2 += (idx == 2); c3 += (idx == 3);
            c4 += (idx == 4); c5 += (idx == 5); c6 += (idx == 6); c7 += (idx == 7);
        }
    }
    part[tid][0] = c0; part[tid][1] = c1; part[tid][2] = c2; part[tid][3] = c3;
    part[tid][4] = c4; part[tid][5] = c5; part[tid][6] = c6; part[tid][7] = c7;
    __syncthreads();
    for (int s = 128; s > 0; s >>= 1) {
        if (tid < s) {
#pragma unroll
            for (int e = 0; e < 8; e++) part[tid][e] += part[tid + s][e];
        }
        __syncthreads();
    }
    if (tid == 0) {
        int run = 0;
        for (int e = 0; e < 8; e++) {
            offsets[e] = run;
            cursor[e]  = run;
            run += part[0][e];
        }
        offsets[8] = run;
    }
}

// K3: scatter + cast + gather fused.
__global__ __launch_bounds__(256) void moe_scatter_gather(
    const float* __restrict__ x,
    const int* __restrict__ topidx,
    int* __restrict__ cursor,
    int* __restrict__ toksort,
    unsigned short* __restrict__ xs) {
    __shared__ int lcnt[8];
    __shared__ int lbase[8];
    __shared__ int s_pos[64];
    int tid = threadIdx.x;
    int base = blockIdx.x << 6;
    if (tid < 8) lcnt[tid] = 0;
    __syncthreads();
    int e = 0, r = 0;
    if (tid < 64) {
        e = topidx[base + tid];
        r = atomicAdd(&lcnt[e], 1);   // LDS atomic
    }
    __syncthreads();
    if (tid < 8) lbase[tid] = atomicAdd(&cursor[tid], lcnt[tid]);
    __syncthreads();
    if (tid < 64) {
        int p = lbase[e] + r;
        toksort[p] = base + tid;
        s_pos[tid] = p;
    }
    __syncthreads();
    for (int rr = 0; rr < 64; rr++) {
        int tok = base + rr;
        int p = s_pos[rr];
        float4 v = *(const float4*)(x + (size_t)tok * D_DIM + (tid << 2));
        ushort4 o;
        o.x = f2bf_bits(v.x); o.y = f2bf_bits(v.y);
        o.z = f2bf_bits(v.z); o.w = f2bf_bits(v.w);
        *(ushort4*)(xs + (size_t)p * D_DIM + (tid << 2)) = o;
    }
}

// fallback scatter (no xs buffer)
__global__ __launch_bounds__(256) void moe_scatter_kernel(
    const int* __restrict__ topidx,
    int* __restrict__ cursor,
    int* __restrict__ toksort) {
    __shared__ int lcnt[8];
    __shared__ int lbase[8];
    int tid = threadIdx.x;
    int t = blockIdx.x * blockDim.x + tid;
    if (tid < 8) lcnt[tid] = 0;
    __syncthreads();
    int e = topidx[t];
    int r = atomicAdd(&lcnt[e], 1);
    __syncthreads();
    if (tid < 8) lbase[tid] = atomicAdd(&cursor[tid], lcnt[tid]);
    __syncthreads();
    toksort[lbase[e] + r] = t;
}

// ---------------------------------------------------------------------------
// ffn1: 256x256 8-phase MFMA GEMM — VERBATIM r2-verified kernel (passed
// harness; active-period throughput ~835 TF-equiv = 2x the 2-phase core).
// 576 blocks at 1 block/CU -> 3 scheduling rounds; expected ~115-135us.
// ---------------------------------------------------------------------------
__device__ __forceinline__ int find_tile256(const int* offsets, int mt,
                                            int& row0, int& rows) {
    int cum = 0;
    for (int ee = 0; ee < E_NUM; ee++) {
        int o0 = offsets[ee], o1 = offsets[ee + 1];
        int tiles = (o1 - o0 + 255) >> 8;
        if (mt < cum + tiles) {
            row0 = o0 + ((mt - cum) << 8);
            rows = o1 - row0; if (rows > 256) rows = 256;
            return ee;
        }
        cum += tiles;
    }
    return -1;
}

#define MMQ(Q, NQ)                                                            \
    _Pragma("unroll") for (int mi = 0; mi < 4; mi++)                          \
    _Pragma("unroll") for (int ni = 0; ni < 2; ni++)                          \
    _Pragma("unroll") for (int kk = 0; kk < 2; kk++)                          \
        acc[(Q)*4 + mi][(NQ)*2 + ni] = __builtin_amdgcn_mfma_f32_16x16x32_bf16( \
            af[mi][kk], bf[ni][kk], acc[(Q)*4 + mi][(NQ)*2 + ni], 0, 0, 0);

#define VMC6 asm volatile("s_waitcnt vmcnt(6)" ::: "memory")
#define VMC8 asm volatile("s_waitcnt vmcnt(8)" ::: "memory")
#define VMNO ((void)0)

#define PHASE(RDS, STG, Q, NQ, VM)                                            \
    RDS;                                                                      \
    STG;                                                                      \
    __builtin_amdgcn_sched_barrier(0);                                        \
    __builtin_amdgcn_s_barrier();                                             \
    asm volatile("s_waitcnt lgkmcnt(0)" ::: "memory");                        \
    __builtin_amdgcn_sched_barrier(0);                                        \
    __builtin_amdgcn_s_setprio(1);                                            \
    MMQ(Q, NQ);                                                               \
    __builtin_amdgcn_s_setprio(0);                                            \
    VM;                                                                       \
    __builtin_amdgcn_s_barrier();                                             \
    __builtin_amdgcn_sched_barrier(0);

template<int LDK>
__device__ __forceinline__ void gemm256_kloop(
    const unsigned short* __restrict__ Ag,
    const unsigned short* __restrict__ Bg,
    int row0, int n0, int ntiles,
    unsigned short* LDSU, floatx4 (&acc)[8][4]) {

    const int tid = threadIdx.x;
    const int l = tid & 63, w = tid >> 6;
    const int lq = l >> 4, lrow = l & 15, l3 = l >> 3;
    const int wm = w & 1, wn = w >> 1;
    const int kc = ((l & 7) ^ (l3 & 7)) << 3;      // pre-swizzled src k elems
    const int gx = l & 7;                          // read-side swizzle term

    const unsigned short* pA[2][2];
    const unsigned short* pB[2][2];
#pragma unroll
    for (int j = 0; j < 2; j++) {
        int s = w * 16 + j * 8 + l3;
#pragma unroll
        for (int h = 0; h < 2; h++) {
            int rA = (s & 63) + h * 64 + ((s >> 6) & 1) * 128;
            int pr = row0 + rA; if (pr > N_TOK - 1) pr = N_TOK - 1;
            pA[j][h] = Ag + (size_t)pr * LDK + kc;
            int cB = (s & 31) + h * 32 + (s >> 5) * 64;
            pB[j][h] = Bg + (size_t)(n0 + cB) * LDK + kc;
        }
    }
    unsigned short* ldsA = LDSU;
    unsigned short* ldsB = LDSU + 32768;
    const int wslot = w * 1024;

    auto STA = [&](int buf, int half, int t) {
        async16(pA[0][half] + ((size_t)t << 6),
                ldsA + buf * 16384 + half * 8192 + wslot);
        async16(pA[1][half] + ((size_t)t << 6),
                ldsA + buf * 16384 + half * 8192 + wslot + 512);
    };
    auto STB = [&](int buf, int half, int t) {
        async16(pB[0][half] + ((size_t)t << 6),
                ldsB + buf * 16384 + half * 8192 + wslot);
        async16(pB[1][half] + ((size_t)t << 6),
                ldsB + buf * 16384 + half * 8192 + wslot + 512);
    };

    short8 af[4][2], bf[2][2];
    const int asb = wm * 64 + lrow;
    const int bsb = wn * 32 + lrow;
    auto RA = [&](int buf, int q) {
        const unsigned short* Ab = ldsA + buf * 16384 + q * 8192;
#pragma unroll
        for (int mi = 0; mi < 4; mi++) {
            int slot = asb + mi * 16;
#pragma unroll
            for (int kk = 0; kk < 2; kk++) {
                int g = (kk * 4 + lq) ^ gx;
                af[mi][kk] = *(const short8*)(Ab + slot * 64 + g * 8);
            }
        }
    };
    auto RB = [&](int buf, int nq) {
        const unsigned short* Bb = ldsB + buf * 16384 + nq * 8192;
#pragma unroll
        for (int ni = 0; ni < 2; ni++) {
            int slot = bsb + ni * 16;
#pragma unroll
            for (int kk = 0; kk < 2; kk++) {
                int g = (kk * 4 + lq) ^ gx;
                bf[ni][kk] = *(const short8*)(Bb + slot * 64 + g * 8);
            }
        }
    };

    STA(0, 0, 0); STB(0, 0, 0); STA(0, 1, 0); STB(0, 1, 0);
    STA(1, 0, 1); STB(1, 0, 1);
    VMC8;
    __builtin_amdgcn_s_barrier();
    __builtin_amdgcn_sched_barrier(0);

    const int NT2 = ntiles >> 1;
    for (int i = 0; i < NT2; i++) {
        const int t1 = 2 * i + 1;
        int t2 = 2 * i + 2; if (t2 > ntiles - 1) t2 = ntiles - 1;
        int t3 = 2 * i + 3; if (t3 > ntiles - 1) t3 = ntiles - 1;
        PHASE((RA(0, 0), RB(0, 0)), STA(1, 1, t1), 0, 0, VMC6);   // p0
        PHASE((RB(0, 1)),           STB(1, 1, t1), 0, 1, VMNO);   // p1
        PHASE((RA(0, 1), RB(0, 0)), STA(0, 0, t2), 1, 0, VMNO);   // p2
        PHASE((RB(0, 1)),           STB(0, 0, t2), 1, 1, VMC8);   // p3
        PHASE((RA(1, 0), RB(1, 0)), STA(0, 1, t2), 0, 0, VMC6);   // p4
        PHASE((RB(1, 1)),           STB(0, 1, t2), 0, 1, VMNO);   // p5
        PHASE((RA(1, 1), RB(1, 0)), STA(1, 0, t3), 1, 0, VMNO);   // p6
        PHASE((RB(1, 1)),           STB(1, 0, t3), 1, 1, VMC8);   // p7
    }
    asm volatile("s_waitcnt vmcnt(0)" ::: "memory");
    __syncthreads();
}

__global__ __launch_bounds__(512, 2) void moe_ffn1_256(
    const unsigned short* __restrict__ xs,
    const unsigned short* __restrict__ W1t,   // [E][H][D] bf16
    const float* __restrict__ b1,
    const int* __restrict__ offsets,
    unsigned short* __restrict__ hb) {        // [N][H] bf16, sorted order

    __shared__ __align__(16) unsigned short LDSU[65536];   // 128 KB

    // T1: bijective XCD swizzle (part of the r2-verified kernel)
    int nwgx = gridDim.x;
    int nwg = nwgx * gridDim.y;
    int id = blockIdx.y * nwgx + blockIdx.x;
    int q8 = nwg >> 3, r8 = nwg & 7;
    int xcd = id & 7, rank = id >> 3;
    int swz = (xcd < r8 ? xcd * (q8 + 1) : r8 * (q8 + 1) + (xcd - r8) * q8) + rank;
    int bx = swz % nwgx, by = swz / nwgx;

    int row0, rows;
    int e = find_tile256(offsets, bx, row0, rows);
    if (e < 0) return;
    int n0 = by << 8;

    const unsigned short* Be = W1t + (size_t)e * H_DIM * D_DIM;

    floatx4 acc[8][4];
#pragma unroll
    for (int mi = 0; mi < 8; mi++)
#pragma unroll
        for (int ni = 0; ni < 4; ni++) acc[mi][ni] = floatx4{0.f, 0.f, 0.f, 0.f};

    gemm256_kloop<D_DIM>(xs, Be, row0, n0, D_DIM / 64, LDSU, acc);

    const int tid = threadIdx.x;
    const int l = tid & 63, w = tid >> 6;
    const int lq = l >> 4, lrow = l & 15;
    const int wm = w & 1, wn = w >> 1;

    float bias[4];
#pragma unroll
    for (int ni = 0; ni < 4; ni++)
        bias[ni] = b1[e * H_DIM + n0 + wn * 64 + ni * 16 + lrow];

    // bias+relu+bf16 into LDS, then coalesced copy out
#pragma unroll
    for (int mi = 0; mi < 8; mi++) {
#pragma unroll
        for (int ni = 0; ni < 4; ni++) {
#pragma unroll
            for (int rr = 0; rr < 4; rr++) {
                int rl = wm * 128 + mi * 16 + lq * 4 + rr;
                int cl = wn * 64 + ni * 16 + lrow;
                float v = acc[mi][ni][rr] + bias[ni];
                v = v > 0.f ? v : 0.f;
                LDSU[rl * 256 + cl] = f2bf_bits(v);
            }
        }
    }
    __syncthreads();
    int trow = tid >> 1, tcol = (tid & 1) << 7;
    if (trow < rows) {
        unsigned short* dst = hb + (size_t)(row0 + trow) * H_DIM + n0 + tcol;
        const unsigned short* src = LDSU + trow * 256 + tcol;
#pragma unroll
        for (int i2 = 0; i2 < 16; i2++)
            *(short8*)(dst + i2 * 8) = *(const short8*)(src + i2 * 8);
    }
}

// ---------------------------------------------------------------------------
// ffn2: EXACT round-1 2-phase kernel (best measured config for 288-task
// shape; 8-phase 256^2 loses to tail quantization here: 2x82=164 > 125).
// ---------------------------------------------------------------------------
__device__ __forceinline__ int find_tile(const int* offsets, int mt,
                                         int& row0, int& rows) {
    int cum = 0;
    for (int ee = 0; ee < E_NUM; ee++) {
        int o0 = offsets[ee], o1 = offsets[ee + 1];
        int tiles = (o1 - o0 + 127) >> 7;
        if (mt < cum + tiles) {
            row0 = o0 + ((mt - cum) << 7);
            rows = o1 - row0; if (rows > 128) rows = 128;
            return ee;
        }
        cum += tiles;
    }
    return -1;
}

__global__ __launch_bounds__(256) void moe_ffn2_mfma(
    const unsigned short* __restrict__ hb,    // [N][H] bf16 sorted
    const unsigned short* __restrict__ W2t,   // [E][D][H] bf16
    const float* __restrict__ b2,
    const int* __restrict__ offsets,
    const int* __restrict__ toksort,
    const float* __restrict__ topw,
    float* __restrict__ out) {

    __shared__ __align__(16) unsigned short As[128 * 32];
    __shared__ __align__(16) unsigned short Bs[128 * 32];

    int row0, rows;
    int e = find_tile(offsets, blockIdx.x, row0, rows);
    if (e < 0) return;
    int n0 = blockIdx.y << 7;

    int tid = threadIdx.x, l = tid & 63, w = tid >> 6;
    int wm = w & 1, wn = w >> 1;
    int lrow = l & 15, lq = l >> 4;
    const unsigned short* Be = W2t + (size_t)e * D_DIM * H_DIM;

    floatx4 acc[4][4];
#pragma unroll
    for (int mi = 0; mi < 4; mi++)
#pragma unroll
        for (int ni = 0; ni < 4; ni++) acc[mi][ni] = floatx4{0.f, 0.f, 0.f, 0.f};

    int srow = (w << 5) + (l >> 2);
    int koff = (l & 3) << 3;

    for (int kt = 0; kt < H_DIM / 32; kt++) {
        int kb = kt << 5;
        __syncthreads();
#pragma unroll
        for (int i = 0; i < 2; i++) {
            int r = srow + (i << 4);
            int p = row0 + r; if (p > N_TOK - 1) p = N_TOK - 1;
            async16(hb + (size_t)p * H_DIM + kb + koff,
                    As + (((w << 5) + (i << 4)) << 5));
            async16(Be + (size_t)(n0 + r) * H_DIM + kb + koff,
                    Bs + (((w << 5) + (i << 4)) << 5));
        }
        __syncthreads();
        short8 af[4], bfv[4];
#pragma unroll
        for (int mi = 0; mi < 4; mi++)
            af[mi] = *(const short8*)(As + (((wm << 6) + (mi << 4) + lrow) << 5) + (lq << 3));
#pragma unroll
        for (int ni = 0; ni < 4; ni++)
            bfv[ni] = *(const short8*)(Bs + (((wn << 6) + (ni << 4) + lrow) << 5) + (lq << 3));
#pragma unroll
        for (int mi = 0; mi < 4; mi++)
#pragma unroll
            for (int ni = 0; ni < 4; ni++)
                acc[mi][ni] = __builtin_amdgcn_mfma_f32_16x16x32_bf16(
                    af[mi], bfv[ni], acc[mi][ni], 0, 0, 0);
    }

    float bias[4];
#pragma unroll
    for (int ni = 0; ni < 4; ni++)
        bias[ni] = b2[e * D_DIM + n0 + (wn << 6) + (ni << 4) + lrow];

#pragma unroll
    for (int mi = 0; mi < 4; mi++) {
#pragma unroll
        for (int r = 0; r < 4; r++) {
            int row = (wm << 6) + (mi << 4) + (lq << 2) + r;
            if (row < rows) {
                int p = row0 + row;
                int tok = toksort[p];
                float tw = topw[tok];
#pragma unroll
                for (int ni = 0; ni < 4; ni++) {
                    int d = n0 + (wn << 6) + (ni << 4) + lrow;
                    out[(size_t)tok * D_DIM + d] = tw * (acc[mi][ni][r] + bias[ni]);
                }
            }
        }
    }
}

// ---------------------------------------------------------------------------
// scalar fallback FFN — used only if ws too small
// ---------------------------------------------------------------------------
__global__ __launch_bounds__(FFN_BLK, 2) void moe_ffn_kernel(
    const float* __restrict__ x,
    const float* __restrict__ W1, const float* __restrict__ b1,
    const float* __restrict__ W2, const float* __restrict__ b2,
    const int* __restrict__ offsets,
    const int* __restrict__ toksort,
    const float* __restrict__ topw,
    float* __restrict__ out) {

    __shared__ __align__(16) unsigned short h1c[MT * 1024];
    float* xs = (float*)h1c;

    int bid = blockIdx.x;
    int e = -1, row0 = 0, rows = 0, cum = 0;
    for (int ee = 0; ee < E_NUM; ee++) {
        int o0 = offsets[ee], o1 = offsets[ee + 1];
        int tiles = (o1 - o0 + MT - 1) / MT;
        if (bid < cum + tiles) {
            e = ee;
            row0 = o0 + (bid - cum) * MT;
            rows = (o1 - row0 < MT) ? (o1 - row0) : MT;
            break;
        }
        cum += tiles;
    }
    if (e < 0) return;

    int tid = threadIdx.x;
    const float* W1e = W1 + (size_t)e * D_DIM * H_DIM;
    const float* W2e = W2 + (size_t)e * H_DIM * D_DIM;

    int m_st = tid >> 4;
    int j_st = tid & 15;
    int m_cl = (m_st < rows) ? m_st : (rows - 1);
    int tok_st = toksort[row0 + m_cl];

    float acc2x[MT], acc2y[MT];
#pragma unroll
    for (int m = 0; m < MT; m++) { acc2x[m] = 0.f; acc2y[m] = 0.f; }

    int d0 = tid * 2;

    for (int half = 0; half < 2; half++) {
        int ha = half * 1024 + tid;
        int hb_ = ha + 512;

        float a1a[MT], a1b[MT];
#pragma unroll
        for (int m = 0; m < MT; m++) { a1a[m] = 0.f; a1b[m] = 0.f; }

        for (int dc = 0; dc < 8; dc++) {
            __syncthreads();
            {
                const float4* src =
                    (const float4*)(x + (size_t)tok_st * D_DIM + dc * 128 + j_st * 8);
                float4 v0 = src[0], v1 = src[1];
                float4* dst = (float4*)(xs + m_st * 128 + j_st * 8);
                dst[0] = v0; dst[1] = v1;
            }
            __syncthreads();
            const float* w1pa = W1e + (size_t)(dc * 128) * H_DIM + ha;
            const float* w1pb = W1e + (size_t)(dc * 128) * H_DIM + hb_;
            for (int d2 = 0; d2 < 64; d2++) {
                float wa0 = w1pa[0], wa1 = w1pa[H_DIM];
                float wb0 = w1pb[0], wb1 = w1pb[H_DIM];
                w1pa += 2 * H_DIM; w1pb += 2 * H_DIM;
#pragma unroll
                for (int m = 0; m < MT; m++) {
                    float2 xv = *(const float2*)(xs + m * 128 + d2 * 2);
                    a1a[m] += xv.x * wa0; a1a[m] += xv.y * wa1;
                    a1b[m] += xv.x * wb0; a1b[m] += xv.y * wb1;
                }
            }
        }

        float bba = b1[e * H_DIM + ha];
        float bbb = b1[e * H_DIM + hb_];
        __syncthreads();
#pragma unroll
        for (int m = 0; m < MT; m++) {
            float va = a1a[m] + bba; va = va > 0.f ? va : 0.f;
            float vb = a1b[m] + bbb; vb = vb > 0.f ? vb : 0.f;
            h1c[m * 1024 + tid]       = f2bf_bits(va);
            h1c[m * 1024 + 512 + tid] = f2bf_bits(vb);
        }
        __syncthreads();

        const float* w2p = W2e + (size_t)(half * 1024) * D_DIM + d0;
        for (int hh = 0; hh < 1024; hh += 2) {
            float2 w2a = *(const float2*)(w2p);
            float2 w2b = *(const float2*)(w2p + D_DIM);
            w2p += 2 * D_DIM;
#pragma unroll
            for (int m = 0; m < MT; m++) {
                unsigned int u = *(const unsigned int*)(h1c + m * 1024 + hh);
                float h0  = __uint_as_float(u << 16);
                float h1v = __uint_as_float(u & 0xffff0000u);
                acc2x[m] += h0 * w2a.x; acc2x[m] += h1v * w2b.x;
                acc2y[m] += h0 * w2a.y; acc2y[m] += h1v * w2b.y;
            }
        }
    }

    float bb0 = b2[e * D_DIM + d0];
    float bb1 = b2[e * D_DIM + d0 + 1];
#pragma unroll
    for (int m = 0; m < MT; m++) {
        if (m < rows) {
            int tok  = toksort[row0 + m];
            float tw = topw[tok];
            float2 o;
            o.x = tw * (acc2x[m] + bb0);
            o.y = tw * (acc2y[m] + bb1);
            *(float2*)(out + (size_t)tok * D_DIM + d0) = o;
        }
    }
}

// ---------------------------------------------------------------------------
extern "C" void kernel_launch(void* const* d_in, const int* in_sizes, int n_in,
                              void* d_out, int out_size, void* d_ws, size_t ws_size,
                              hipStream_t stream) {
    const float* x  = (const float*)d_in[0];
    const float* Wg = (const float*)d_in[1];
    const float* bg = (const float*)d_in[2];
    const float* W1 = (const float*)d_in[3];
    const float* b1 = (const float*)d_in[4];
    const float* W2 = (const float*)d_in[5];
    const float* b2 = (const float*)d_in[6];

    float* out = (float*)d_out;
    float* gw  = out + (size_t)N_TOK * D_DIM;

    char* ws = (char*)d_ws;
    int*   counts  = (int*)ws;            // 8 (unused, layout kept)
    int*   cursor  = counts + 8;          // 8
    int*   offsets = cursor + 8;          // 9
    int*   topidx  = (int*)(ws + 128);
    float* topw    = (float*)(ws + 128 + 4 * (size_t)N_TOK);
    int*   toksort = (int*)(ws + 128 + 8 * (size_t)N_TOK);

    const size_t off_xs  = 256ull << 10;
    const size_t off_w1t = off_xs  + (32ull << 20);
    const size_t off_w2t = off_w1t + (32ull << 20);
    const size_t off_hb  = off_w2t + (32ull << 20);
    const size_t need    = off_hb  + (64ull << 20);

    if (ws_size >= need) {
        unsigned short* xs  = (unsigned short*)(ws + off_xs);
        unsigned short* W1t = (unsigned short*)(ws + off_w1t);
        unsigned short* W2t = (unsigned short*)(ws + off_w2t);
        unsigned short* hb  = (unsigned short*)(ws + off_hb);

        moe_gate_transpose_fused<<<12288, 256, 0, stream>>>(
            x, Wg, bg, gw, topw, topidx, W1, W2, W1t, W2t);
        moe_hist_scan_kernel<<<1, 256, 0, stream>>>(topidx, offsets, cursor);
        moe_scatter_gather<<<N_TOK / 64, 256, 0, stream>>>(
            x, topidx, cursor, toksort, xs);

        moe_ffn1_256<<<dim3(N_TOK / 256 + E_NUM, H_DIM / 256), 512, 0, stream>>>(
            xs, W1t, b1, offsets, hb);
        moe_ffn2_mfma<<<dim3(N_TOK / 128 + E_NUM, D_DIM / 128), 256, 0, stream>>>(
            hb, W2t, b2, offsets, toksort, topw, out);
    } else {
        moe_gate_kernel<<<N_TOK / 4, 256, 0, stream>>>(
            x, Wg, bg, gw, topw, topidx);
        moe_hist_scan_kernel<<<1, 256, 0, stream>>>(topidx, offsets, cursor);
        moe_scatter_kernel<<<N_TOK / 256, 256, 0, stream>>>(topidx, cursor, toksort);
        moe_ffn_kernel<<<N_TOK / MT + E_NUM, FFN_BLK, 0, stream>>>(
            x, W1, b1, W2, b2, offsets, toksort, topw, out);
    }
}